// Round 11
// baseline (406.426 us; speedup 1.0000x reference)
//
#include <hip/hip_runtime.h>
#include <hip/hip_bf16.h>

#define TT 6
#define NN 50000
#define EE 800000
#define FF 32
#define HH 64
#define OO 16

#define NB 256        // dst buckets
#define DPB 196       // dsts per bucket (256*196 = 50176 >= 50000)
#define DEGN 50176    // NB*DPB padded node count per t
#define CHUNK 4096    // edges per block in scatter
#define CAP 4096      // slab capacity per (t,bucket): mean 3125, sd 56 -> 17 sigma
#define SCAP 4608     // 8-aligned-chain LDS capacity: mean 3811, sd ~32 -> 12 sigma

#define WFRAG_N 19456  // 38 slots * 512 bf16 fragment-packed weights
// wbias layout: [0..63] cz, [64..127] cr, [128..191] ch, [192..207] out_b

typedef unsigned short ushort_t;
typedef unsigned char uchar_t;
typedef short short8 __attribute__((ext_vector_type(8)));   // 8 bf16 (4 VGPRs)
typedef float f32x4 __attribute__((ext_vector_type(4)));
typedef float f32x2 __attribute__((ext_vector_type(2)));

__device__ __forceinline__ float ubf(ushort_t v){ return __uint_as_float(((unsigned)v) << 16); }
__device__ __forceinline__ ushort_t f2b(float f){
  unsigned u = __float_as_uint(f);
  return (ushort_t)((u + 0x7FFFu + ((u >> 16) & 1u)) >> 16);
}
__device__ __forceinline__ float lo16f(unsigned u){ return __uint_as_float(u << 16); }
__device__ __forceinline__ float hi16f(unsigned u){ return __uint_as_float(u & 0xFFFF0000u); }

// LESSON (v7/v8): LDS *float* atomics on gfx950 are lane-serialized (~820us for
// 153M) -- never bulk f32 LDS atomics. Int LDS atomics are fine.
// LESSON (v11/R9): blocks dispatch round-robin to XCDs (l%8) and the whole grid
// is co-resident; identity (t,b) mapping puts ALL 6 t-slices (19.2MB) on every
// XCD's L2 -> FETCH 243MB, 80us. The contiguous-range swizzle wk=(l&7)*192+(l>>3)
// bounds each XCD to <=2 slices (6.4MB) and is near-optimal.

// ---------------- fused prep: wfrag + biases + bcur/deg zero -------------------
__global__ void prepall_kernel(const float* __restrict__ Wz,const float* __restrict__ bz,
                               const float* __restrict__ Wr,const float* __restrict__ br,
                               const float* __restrict__ Wh,const float* __restrict__ bh,
                               const float* __restrict__ Lz,const float* __restrict__ Lzb,
                               const float* __restrict__ Lr,const float* __restrict__ Lrb,
                               const float* __restrict__ Lh,const float* __restrict__ Lhb,
                               const float* __restrict__ oW,const float* __restrict__ ob,
                               short* __restrict__ wfrag, float* __restrict__ wbias,
                               int* __restrict__ bcur, int* __restrict__ deg){
  int bid = blockIdx.x, tid = threadIdx.x;
  if (bid < 76){
    int idx = bid*256 + tid;   // 0..19455
    int slot = idx >> 9, lane = (idx >> 3) & 63, j = idx & 7;
    int q = lane >> 4, l15 = lane & 15;
    float val;
    if (slot < 36){
      int g, kc, ncol;
      if (slot < 24){ int nt = slot/3; kc = slot - nt*3; ncol = nt*16 + l15;
                      g = (ncol < 64) ? 0 : 1; ncol &= 63; }
      else          { int s2 = slot-24; int nt = s2/3; kc = s2 - nt*3;
                      ncol = nt*16 + l15; g = 2; }
      const float* W = (g==0)?Wz:((g==1)?Wr:Wh);     // [32][64]
      const float* L = (g==0)?Lz:((g==1)?Lr:Lh);     // [128][64]
      int k = kc*32 + q*8 + j;                        // 0..95
      if (k < 32){                                    // fused W@L[:64]
        float s = 0.f;
        for (int m = 0; m < 64; m++) s += W[k*64+m] * L[m*64+ncol];
        val = s;
      } else val = L[(32+k)*64 + ncol];               // L rows 64..127
    } else {
      int kc = slot - 36;
      int k = kc*32 + q*8 + j;                        // 0..63
      val = oW[k*16 + l15];
    }
    wfrag[idx] = (short)f2b(val);
  } else if (bid == 76){
    if (tid < 192){
      int g = tid >> 6, j = tid & 63;
      const float* L  = (g==0)?Lz:((g==1)?Lr:Lh);
      const float* bb = (g==0)?bz:((g==1)?br:bh);
      const float* Lb = (g==0)?Lzb:((g==1)?Lrb:Lhb);
      float s = Lb[j];
      for (int m = 0; m < 64; m++) s += bb[m] * L[m*64+j];
      wbias[tid] = s;
    } else if (tid < 208){
      wbias[tid] = ob[tid-192];
    }
    for (int i = tid; i < 1536; i += 256) bcur[i] = 0;
  } else {
    // zero deg: 294 blocks x 256 threads x int4 = 301,056 ints exactly
    int i = (bid - 77)*1024 + tid*4;
    if (i < TT*DEGN) *(int4*)&deg[i] = make_int4(0,0,0,0);
  }
}

// ---------------- scatter: LDS counting-sort by bucket + global deg count ------
__global__ __launch_bounds__(256) void scatter_kernel(const int* __restrict__ ei,
                                                      int* __restrict__ bcur,
                                                      ushort_t* __restrict__ ssrc16,
                                                      uchar_t* __restrict__ sdst8,
                                                      int* __restrict__ deg){
  int t = blockIdx.y;
  __shared__ int cnt[NB];
  __shared__ int lstart[NB];
  __shared__ int gbase[NB];
  __shared__ int wsum[4];
  __shared__ ushort_t spay[CHUNK];
  __shared__ uchar_t  sdlo[CHUNK];
  __shared__ uchar_t  sbk[CHUNK];
  int tid = threadIdx.x;
  cnt[tid] = 0;
  __syncthreads();
  int e0 = blockIdx.x*CHUNK;
  const int* srcs = ei + t*2*EE;
  const int* dsts = ei + t*2*EE + EE;
  int* degt = deg + (size_t)t*DEGN;
  int pk[CHUNK/256];
  int ps[CHUNK/256];
  int pd[CHUNK/256];
  #pragma unroll
  for (int i = 0; i < CHUNK/256; i++){
    int e = e0 + i*256 + tid;
    if (e < EE){
      int s = srcs[e], d = dsts[e];
      int b = d / DPB;
      int lr = atomicAdd(&cnt[b], 1);
      atomicAdd(&degt[d], 1);         // fire-and-forget global deg count
      pk[i] = (b << 12) | lr;
      ps[i] = s;
      pd[i] = d - b*DPB;
    } else pk[i] = -1;
  }
  __syncthreads();
  {
    int v = cnt[tid];
    int lane = tid & 63, wid = tid >> 6;
    int x = v;
    #pragma unroll
    for (int o = 1; o < 64; o <<= 1){
      int y = __shfl_up(x, o, 64);
      if (lane >= o) x += y;
    }
    if (lane == 63) wsum[wid] = x;
    __syncthreads();
    if (tid == 0){
      int s = 0;
      #pragma unroll
      for (int w = 0; w < 4; w++){ int tmp = wsum[w]; wsum[w] = s; s += tmp; }
    }
    __syncthreads();
    lstart[tid] = x - v + wsum[wid];
    gbase[tid] = (v > 0) ? atomicAdd(&bcur[t*NB + tid], v) : 0;
  }
  __syncthreads();
  #pragma unroll
  for (int i = 0; i < CHUNK/256; i++){
    if (pk[i] >= 0){
      int b = pk[i] >> 12, lr = pk[i] & 4095;
      int pos = lstart[b] + lr;
      spay[pos] = (ushort_t)ps[i];
      sdlo[pos] = (uchar_t)pd[i];
      sbk[pos]  = (uchar_t)b;
    }
  }
  __syncthreads();
  int nE = EE - e0; if (nE > CHUNK) nE = CHUNK;
  for (int i = tid; i < nE; i += 256){
    int b = sbk[i];
    int gpos = gbase[b] + (i - lstart[b]);
    if (gpos < CAP){
      size_t sb = (size_t)(t*NB + b)*CAP + gpos;
      ssrc16[sb] = spay[i];
      sdst8[sb]  = sdlo[i];
    }
  }
}

// ---------------- convert + pre-scale: xbs = bf16(rsqrt(deg+1) * x) ------------
__global__ void cvtscale_kernel(const float4* __restrict__ x4,
                                const int* __restrict__ deg,
                                ushort4* __restrict__ xb4){
  int t = blockIdx.y;
  int idx = blockIdx.x*256 + threadIdx.x;   // float4 index within t, NN*8 total
  if (idx < NN*8){
    int n = idx >> 3;
    float dn = rsqrtf((float)(deg[(size_t)t*DEGN + n] + 1));
    float4 v = x4[(size_t)t*NN*8 + idx];
    ushort4 o;
    o.x = f2b(v.x*dn); o.y = f2b(v.y*dn); o.z = f2b(v.z*dn); o.w = f2b(v.w*dn);
    xb4[(size_t)t*NN*8 + idx] = o;
  }
}

// ---------------- bucket gather v13: self-contained sort from global deg -------
// degdinv kernel eliminated: per-dst counts come as 196 coalesced int loads from
// deg (built by scatter's fire-and-forget atomics); scan + 64-class LPT sort are
// block-local on 196 elements (~4 barriers, no slab pass). Reduce loop = v12.
__global__ __launch_bounds__(256) void gatherb_kernel(const ushort_t* __restrict__ xbs,
                                                      const ushort_t* __restrict__ ssrc16,
                                                      const uchar_t* __restrict__ sdst8,
                                                      const int* __restrict__ bcur,
                                                      const int* __restrict__ deg,
                                                      ushort_t* __restrict__ aggb){
  int l = blockIdx.x;
  int wk = ((l & 7) * 192) + (l >> 3);   // XCD l%8 owns contiguous slabs
  int t = wk >> 8;
  int b = wk & 255;
  int tid = threadIdx.x;
  __shared__ __align__(16) ushort_t ssrc[SCAP];  // 9 KB dst-sorted srcs, chains 8-aligned
  __shared__ int sord[DPB];           // rank-indexed packed (off<<19)|(cnt<<8)|dst
  __shared__ int scnt[DPB];           // per-dst place cursor
  __shared__ int wsum[4];
  __shared__ int dbase[64];
  __shared__ int dcur;                // dynamic rank claim cursor
  if (tid < 64) dbase[tid] = 0;
  if (tid == 0) dcur = 0;
  int v = (tid < DPB) ? deg[(size_t)t*DEGN + b*DPB + tid] : 0;
  int pc = (v + 7) & ~7;                      // padded count -> aligned chains
  int lane = tid & 63, wid = tid >> 6;
  {
    int x = pc;
    #pragma unroll
    for (int o = 1; o < 64; o <<= 1){
      int y = __shfl_up(x, o, 64);
      if (lane >= o) x += y;
    }
    if (lane == 63) wsum[wid] = x;
    __syncthreads();                          // wsum + dbase/dcur init visible
    if (tid == 0){
      int s = 0;
      #pragma unroll
      for (int w = 0; w < 4; w++){ int tmp = wsum[w]; wsum[w] = s; s += tmp; }
    }
    __syncthreads();
    int excl = x - pc + wsum[wid];
    int cls = 63 - ((v > 63) ? 63 : v);       // class 0 = largest degree
    if (tid < DPB){
      scnt[tid] = excl;
      atomicAdd(&dbase[cls], 1);
    }
    __syncthreads();
    if (tid == 0){
      int s = 0;
      for (int i = 0; i < 64; i++){ int c = dbase[i]; dbase[i] = s; s += c; }
    }
    __syncthreads();
    if (tid < DPB){
      int r = atomicAdd(&dbase[cls], 1);
      int cv = (v > 2047) ? 2047 : v;
      sord[r] = (excl << 19) | (cv << 8) | tid;
    }
  }
  __syncthreads();                            // scnt + sord ready
  int ecnt = bcur[t*NB + b]; if (ecnt > CAP) ecnt = CAP;
  size_t slab = (size_t)(t*NB + b)*CAP;
  const ushort_t* sp = ssrc16 + slab;
  const uchar_t*  dp = sdst8 + slab;
  // rank & place (single pass over slab)
  for (int e = tid; e < ecnt; e += 256){
    int d = dp[e];
    int pos = atomicAdd(&scnt[d], 1);
    if (pos < SCAP) ssrc[pos] = sp[e];
  }
  __syncthreads();
  // reduce: 8-lane group claims ranks in LPT order
  int fp = lane & 7;
  const uint2* xb2 = (const uint2*)xbs + (size_t)t*NN*8;
  uint2* agg2 = (uint2*)aggb + (size_t)t*NN*8;
  while (true){
    int r = 0;
    if ((lane & 7) == 0) r = atomicAdd(&dcur, 1);
    r = __shfl(r, lane & 56, 64);
    if (r >= DPB) break;
    int pv = sord[r];
    int e0 = (unsigned)pv >> 19;
    int dg = (pv >> 8) & 2047;
    int ld = pv & 255;
    int e1 = e0 + dg;
    f32x2 a01 = {0.f, 0.f}, a23 = {0.f, 0.f};
    for (int i = e0; i < e1; i += 8){
      short8 sv = *(const short8*)&ssrc[i];   // one b128: 8 src ids (broadcast)
      uint2 rr[8];
      #pragma unroll
      for (int k = 0; k < 8; k++){
        int sidx = (int)(ushort_t)sv[k];
        rr[k] = xb2[(size_t)sidx*8 + fp];
      }
      int rem = e1 - i;
      #pragma unroll
      for (int k = 0; k < 8; k++){
        if (k >= rem){ rr[k].x = 0u; rr[k].y = 0u; }
        f32x2 v01 = {lo16f(rr[k].x), hi16f(rr[k].x)};
        f32x2 v23 = {lo16f(rr[k].y), hi16f(rr[k].y)};
        a01 += v01;
        a23 += v23;
      }
    }
    int n = b*DPB + ld;
    if (n < NN){
      float dn = rsqrtf((float)(dg + 1));       // local degree -> dinv
      uint2 sv = xb2[(size_t)n*8 + fp];         // self term (pre-scaled row)
      float o0 = dn*(a01[0] + lo16f(sv.x));
      float o1 = dn*(a01[1] + hi16f(sv.x));
      float o2 = dn*(a23[0] + lo16f(sv.y));
      float o3 = dn*(a23[1] + hi16f(sv.y));
      uint2 pk;
      pk.x = (unsigned)f2b(o0) | ((unsigned)f2b(o1) << 16);
      pk.y = (unsigned)f2b(o2) | ((unsigned)f2b(o3) << 16);
      agg2[(size_t)n*8 + fp] = pk;
    }
  }
}

// ---------------- ALL GRU steps v2: h in registers, rcp gates, direct A loads ---
__global__ __launch_bounds__(256) void gates_kernel(const ushort_t* __restrict__ aggb,
                                                    const float* __restrict__ wbias,
                                                    const short* __restrict__ wfrag,
                                                    float* __restrict__ out){
  __shared__ __align__(16) short Hsp[4096];   // 64 x 64  (8 KB) swizzled
  __shared__ __align__(16) short HRp[4096];   // 64 x 64  (8 KB) swizzled
  int tid = threadIdx.x;
  int nb = blockIdx.x*64;
  int wv = tid >> 6, lane = tid & 63;
  int q = lane >> 4, l15 = lane & 15;
  #pragma unroll
  for (int r = 0; r < 8; r++) ((int*)Hsp)[tid + 256*r] = 0;
  short8 wz[3], wr[3], wh[3];
  #pragma unroll
  for (int kc = 0; kc < 3; kc++){
    wz[kc] = ((const short8*)wfrag)[(wv*3 + kc)*64 + lane];
    wr[kc] = ((const short8*)wfrag)[((wv+4)*3 + kc)*64 + lane];
    wh[kc] = ((const short8*)wfrag)[(24 + wv*3 + kc)*64 + lane];
  }
  int jz = wv*16 + l15;
  float cz = wbias[jz], cr = wbias[64 + jz], ch = wbias[128 + jz];
  int c0 = jz >> 3, jl = jz & 7, x0 = c0 & 7;
  int sq0 = q & 7, sq1 = (4 + q) & 7;         // swizzle keys for chunk q / 4+q
  float hreg[4][4];
  #pragma unroll
  for (int mt = 0; mt < 4; mt++)
    #pragma unroll
    for (int e = 0; e < 4; e++) hreg[mt][e] = 0.f;
  f32x4 accZ[4], accH[4];
  const short8* agf = (const short8*)aggb;
  for (int t = 0; t < TT; t++){
    // direct global A-fragment loads (issued before barrier; tile is L1-hot)
    short8 fac[4];
    #pragma unroll
    for (int mt = 0; mt < 4; mt++){
      int gn = nb + mt*16 + l15;
      short8 v = {0,0,0,0,0,0,0,0};
      if (gn < NN) v = agf[((size_t)t*NN + gn)*4 + q];
      fac[mt] = v;
    }
    __syncthreads();   // prev-iter Hsp writes visible
    #pragma unroll
    for (int mt = 0; mt < 4; mt++){
      int n = mt*16 + l15;
      short8 fh0 = *(const short8*)&Hsp[((q)*64   + (n ^ sq0))*8];
      short8 fh1 = *(const short8*)&Hsp[((4+q)*64 + (n ^ sq1))*8];
      f32x4 az = {0.f,0.f,0.f,0.f}, ar = {0.f,0.f,0.f,0.f};
      az = __builtin_amdgcn_mfma_f32_16x16x32_bf16(fac[mt], wz[0], az, 0,0,0);
      az = __builtin_amdgcn_mfma_f32_16x16x32_bf16(fh0,     wz[1], az, 0,0,0);
      az = __builtin_amdgcn_mfma_f32_16x16x32_bf16(fh1,     wz[2], az, 0,0,0);
      ar = __builtin_amdgcn_mfma_f32_16x16x32_bf16(fac[mt], wr[0], ar, 0,0,0);
      ar = __builtin_amdgcn_mfma_f32_16x16x32_bf16(fh0,     wr[1], ar, 0,0,0);
      ar = __builtin_amdgcn_mfma_f32_16x16x32_bf16(fh1,     wr[2], ar, 0,0,0);
      accZ[mt] = az; accH[mt] = ar;
    }
    #pragma unroll
    for (int mt = 0; mt < 4; mt++){
      #pragma unroll
      for (int e = 0; e < 4; e++){
        int node = mt*16 + q*4 + e;
        float z = __builtin_amdgcn_rcpf(1.f + __expf(-(accZ[mt][e] + cz)));
        float r = __builtin_amdgcn_rcpf(1.f + __expf(-(accH[mt][e] + cr)));
        HRp[(c0*64 + (node ^ x0))*8 + jl] = (short)f2b(hreg[mt][e] * r);
        accZ[mt][e] = z;
      }
    }
    __syncthreads();   // HRp complete
    #pragma unroll
    for (int mt = 0; mt < 4; mt++){
      int n = mt*16 + l15;
      short8 fr0 = *(const short8*)&HRp[((q)*64   + (n ^ sq0))*8];
      short8 fr1 = *(const short8*)&HRp[((4+q)*64 + (n ^ sq1))*8];
      f32x4 ahh = {0.f,0.f,0.f,0.f};
      ahh = __builtin_amdgcn_mfma_f32_16x16x32_bf16(fac[mt], wh[0], ahh, 0,0,0);
      ahh = __builtin_amdgcn_mfma_f32_16x16x32_bf16(fr0,     wh[1], ahh, 0,0,0);
      ahh = __builtin_amdgcn_mfma_f32_16x16x32_bf16(fr1,     wh[2], ahh, 0,0,0);
      accH[mt] = ahh;
    }
    #pragma unroll
    for (int mt = 0; mt < 4; mt++){
      #pragma unroll
      for (int e = 0; e < 4; e++){
        int node = mt*16 + q*4 + e;
        float xv = accH[mt][e] + ch;
        float ex = __expf(-2.f*fabsf(xv));
        float th = (1.f - ex) * __builtin_amdgcn_rcpf(1.f + ex);
        th = (xv < 0.f) ? -th : th;
        float z = accZ[mt][e];
        float hv = z*hreg[mt][e] + (1.f - z)*th;
        hreg[mt][e] = hv;
        Hsp[(c0*64 + (node ^ x0))*8 + jl] = (short)f2b(hv);
      }
    }
  }
  __syncthreads();
  short8 wo0 = ((const short8*)wfrag)[36*64 + lane];
  short8 wo1 = ((const short8*)wfrag)[37*64 + lane];
  int no = wv*16 + l15;
  short8 f0 = *(const short8*)&Hsp[((q)*64   + (no ^ sq0))*8];
  short8 f1 = *(const short8*)&Hsp[((4+q)*64 + (no ^ sq1))*8];
  f32x4 ao = {0.f,0.f,0.f,0.f};
  ao = __builtin_amdgcn_mfma_f32_16x16x32_bf16(f0, wo0, ao, 0,0,0);
  ao = __builtin_amdgcn_mfma_f32_16x16x32_bf16(f1, wo1, ao, 0,0,0);
  float ob = wbias[192 + l15];
  #pragma unroll
  for (int e = 0; e < 4; e++){
    int gn = nb + wv*16 + q*4 + e;
    if (gn < NN) out[gn*OO + l15] = ao[e] + ob;
  }
}

extern "C" void kernel_launch(void* const* d_in, const int* in_sizes, int n_in,
                              void* d_out, int out_size, void* d_ws, size_t ws_size,
                              hipStream_t stream) {
  const float* xs = (const float*)d_in[0];
  const int*   ei = (const int*)d_in[1];
  float* out = (float*)d_out;
  char* ws = (char*)d_ws;
  // workspace layout (bytes); total 59,724,544 (same proven footprint)
  ushort_t*  aggb   = (ushort_t*)(ws + 0);           // 19,200,000
  ushort_t*  xbs    = (ushort_t*)(ws + 19200000);    // 19,200,000 (pre-scaled bf16)
  ushort_t*  ssrc16 = (ushort_t*)(ws + 38400000);    // 12,582,912
  uchar_t*   sdst8  = (uchar_t*) (ws + 50982912);    //  6,291,456
  // (old dinv slot ws+57274368, 1.2MB: unused)
  int*       bcur   = (int*)     (ws + 58474368);    //  6,144
  short*     wfrag  = (short*)   (ws + 58480512);    //  38,912
  float*     wbias  = (float*)   (ws + 58519424);    //  832
  int*       deg    = (int*)     (ws + 58520320);    //  1,204,224 (TT*DEGN ints) -> end 59,724,544

  prepall_kernel<<<371, 256, 0, stream>>>(
      (const float*)d_in[2],(const float*)d_in[3],(const float*)d_in[4],(const float*)d_in[5],
      (const float*)d_in[6],(const float*)d_in[7],(const float*)d_in[8],(const float*)d_in[9],
      (const float*)d_in[10],(const float*)d_in[11],(const float*)d_in[12],(const float*)d_in[13],
      (const float*)d_in[14],(const float*)d_in[15], wfrag, wbias, bcur, deg);
  scatter_kernel<<<dim3((EE + CHUNK-1)/CHUNK, TT), 256, 0, stream>>>(ei, bcur, ssrc16, sdst8, deg);
  cvtscale_kernel<<<dim3((NN*8 + 255)/256, TT), 256, 0, stream>>>((const float4*)xs, deg, (ushort4*)xbs);
  gatherb_kernel<<<NB*TT, 256, 0, stream>>>(xbs, ssrc16, sdst8, bcur, deg, aggb);
  gates_kernel<<<(NN + 63)/64, 256, 0, stream>>>(aggb, wbias, wfrag, out);
}

// Round 13
// 238.644 us; speedup vs baseline: 1.7031x; 1.7031x over previous
//
#include <hip/hip_runtime.h>
#include <hip/hip_bf16.h>

#define TT 6
#define NN 50000
#define EE 800000
#define FF 32
#define HH 64
#define OO 16

#define NB 256        // dst buckets
#define DPB 196       // dsts per bucket (256*196 = 50176 >= 50000)
#define CHUNK 4096    // edges per block in scatter
#define CAP 4096      // slab capacity per (t,bucket): mean 3125, sd 56 -> 17 sigma
#define SCAP 4608     // 8-aligned-chain LDS capacity: mean 3811, sd ~32 -> 12 sigma

#define WFRAG_N 19456  // 38 slots * 512 bf16 fragment-packed weights
// wbias layout: [0..63] cz, [64..127] cr, [128..191] ch, [192..207] out_b

typedef unsigned short ushort_t;
typedef unsigned char uchar_t;
typedef short short8 __attribute__((ext_vector_type(8)));   // 8 bf16 (4 VGPRs)
typedef float f32x4 __attribute__((ext_vector_type(4)));
typedef float f32x2 __attribute__((ext_vector_type(2)));

__device__ __forceinline__ float ubf(ushort_t v){ return __uint_as_float(((unsigned)v) << 16); }
__device__ __forceinline__ ushort_t f2b(float f){
  unsigned u = __float_as_uint(f);
  return (ushort_t)((u + 0x7FFFu + ((u >> 16) & 1u)) >> 16);
}
__device__ __forceinline__ float lo16f(unsigned u){ return __uint_as_float(u << 16); }
__device__ __forceinline__ float hi16f(unsigned u){ return __uint_as_float(u & 0xFFFF0000u); }

// LESSON (v7/v8): LDS *float* atomics on gfx950 are lane-serialized (~820us for
// 153M) -- never bulk f32 LDS atomics. Int LDS atomics are fine.
// LESSON (v11/R9): blocks dispatch round-robin to XCDs (l%8), whole grid
// co-resident; identity (t,b) mapping -> 19.2MB/XCD L2 working set -> thrash
// (FETCH 243MB, 80us). Contiguous-range swizzle wk=(l&7)*192+(l>>3) is right.
// LESSON (v13/R11): bulk random-address GLOBAL atomics are ~40ns each on gfx950
// (4.8M made scatter 200us, VALUBusy 2.6%, L2 dirty-line thrash). Histogram in
// LDS (int atomics) per block instead.
// NOTE (R12): container failed twice on this exact source; audit found no OOB/
// hang/barrier divergence and footprint = proven 59,724,544B. Resubmitting to
// distinguish infra flake from kernel fault.

// ---------------- fused prep: wfrag (direct from raw weights) + biases + bcur zero
__global__ void prepall_kernel(const float* __restrict__ Wz,const float* __restrict__ bz,
                               const float* __restrict__ Wr,const float* __restrict__ br,
                               const float* __restrict__ Wh,const float* __restrict__ bh,
                               const float* __restrict__ Lz,const float* __restrict__ Lzb,
                               const float* __restrict__ Lr,const float* __restrict__ Lrb,
                               const float* __restrict__ Lh,const float* __restrict__ Lhb,
                               const float* __restrict__ oW,const float* __restrict__ ob,
                               short* __restrict__ wfrag, float* __restrict__ wbias,
                               int* __restrict__ bcur){
  int bid = blockIdx.x, tid = threadIdx.x;
  if (bid < 76){
    int idx = bid*256 + tid;   // 0..19455
    int slot = idx >> 9, lane = (idx >> 3) & 63, j = idx & 7;
    int q = lane >> 4, l15 = lane & 15;
    float val;
    if (slot < 36){
      int g, kc, ncol;
      if (slot < 24){ int nt = slot/3; kc = slot - nt*3; ncol = nt*16 + l15;
                      g = (ncol < 64) ? 0 : 1; ncol &= 63; }
      else          { int s2 = slot-24; int nt = s2/3; kc = s2 - nt*3;
                      ncol = nt*16 + l15; g = 2; }
      const float* W = (g==0)?Wz:((g==1)?Wr:Wh);     // [32][64]
      const float* L = (g==0)?Lz:((g==1)?Lr:Lh);     // [128][64]
      int k = kc*32 + q*8 + j;                        // 0..95
      if (k < 32){                                    // fused W@L[:64]
        float s = 0.f;
        for (int m = 0; m < 64; m++) s += W[k*64+m] * L[m*64+ncol];
        val = s;
      } else val = L[(32+k)*64 + ncol];               // L rows 64..127
    } else {
      int kc = slot - 36;
      int k = kc*32 + q*8 + j;                        // 0..63
      val = oW[k*16 + l15];
    }
    wfrag[idx] = (short)f2b(val);
  } else {
    if (tid < 192){
      int g = tid >> 6, j = tid & 63;
      const float* L  = (g==0)?Lz:((g==1)?Lr:Lh);
      const float* bb = (g==0)?bz:((g==1)?br:bh);
      const float* Lb = (g==0)?Lzb:((g==1)?Lrb:Lhb);
      float s = Lb[j];
      for (int m = 0; m < 64; m++) s += bb[m] * L[m*64+j];
      wbias[tid] = s;
    } else if (tid < 208){
      wbias[tid] = ob[tid-192];
    }
    for (int i = tid; i < 1536; i += 256) bcur[i] = 0;
  }
}

// ---------------- scatter: LDS counting-sort by bucket -> coalesced slab writes --
__global__ __launch_bounds__(256) void scatter_kernel(const int* __restrict__ ei,
                                                      int* __restrict__ bcur,
                                                      ushort_t* __restrict__ ssrc16,
                                                      uchar_t* __restrict__ sdst8){
  int t = blockIdx.y;
  __shared__ int cnt[NB];
  __shared__ int lstart[NB];
  __shared__ int gbase[NB];
  __shared__ int wsum[4];
  __shared__ ushort_t spay[CHUNK];
  __shared__ uchar_t  sdlo[CHUNK];
  __shared__ uchar_t  sbk[CHUNK];
  int tid = threadIdx.x;
  cnt[tid] = 0;
  __syncthreads();
  int e0 = blockIdx.x*CHUNK;
  const int* srcs = ei + t*2*EE;
  const int* dsts = ei + t*2*EE + EE;
  int pk[CHUNK/256];
  int ps[CHUNK/256];
  int pd[CHUNK/256];
  #pragma unroll
  for (int i = 0; i < CHUNK/256; i++){
    int e = e0 + i*256 + tid;
    if (e < EE){
      int s = srcs[e], d = dsts[e];
      int b = d / DPB;
      int lr = atomicAdd(&cnt[b], 1);
      pk[i] = (b << 12) | lr;
      ps[i] = s;
      pd[i] = d - b*DPB;
    } else pk[i] = -1;
  }
  __syncthreads();
  {
    int v = cnt[tid];
    int lane = tid & 63, wid = tid >> 6;
    int x = v;
    #pragma unroll
    for (int o = 1; o < 64; o <<= 1){
      int y = __shfl_up(x, o, 64);
      if (lane >= o) x += y;
    }
    if (lane == 63) wsum[wid] = x;
    __syncthreads();
    if (tid == 0){
      int s = 0;
      #pragma unroll
      for (int w = 0; w < 4; w++){ int tmp = wsum[w]; wsum[w] = s; s += tmp; }
    }
    __syncthreads();
    lstart[tid] = x - v + wsum[wid];
    gbase[tid] = (v > 0) ? atomicAdd(&bcur[t*NB + tid], v) : 0;
  }
  __syncthreads();
  #pragma unroll
  for (int i = 0; i < CHUNK/256; i++){
    if (pk[i] >= 0){
      int b = pk[i] >> 12, lr = pk[i] & 4095;
      int pos = lstart[b] + lr;
      spay[pos] = (ushort_t)ps[i];
      sdlo[pos] = (uchar_t)pd[i];
      sbk[pos]  = (uchar_t)b;
    }
  }
  __syncthreads();
  int nE = EE - e0; if (nE > CHUNK) nE = CHUNK;
  for (int i = tid; i < nE; i += 256){
    int b = sbk[i];
    int gpos = gbase[b] + (i - lstart[b]);
    if (gpos < CAP){
      size_t sb = (size_t)(t*NB + b)*CAP + gpos;
      ssrc16[sb] = spay[i];
      sdst8[sb]  = sdlo[i];
    }
  }
}

// ---------------- degree + LPT order + fused convert/pre-scale -----------------
// = R10's degdinv (histogram from slab via LDS int atomics, scan, 64-class LPT
// sort -> rank-packed ordg) PLUS the cvtscale work for this block's own 196
// nodes, using dinv straight from LDS. Kills the separate cvtscale launch and
// the dinv global array entirely.
__global__ __launch_bounds__(256) void degcvt_kernel(const uchar_t* __restrict__ sdst8,
                                                     const int* __restrict__ bcur,
                                                     const float4* __restrict__ x4,
                                                     ushort4* __restrict__ xb4,
                                                     int* __restrict__ ordg){
  int b = blockIdx.x, t = blockIdx.y, tid = threadIdx.x;
  __shared__ int cnt[DPB];
  __shared__ int wsum[4];
  __shared__ int dbase[64];
  __shared__ float sdinv[DPB];
  for (int i = tid; i < DPB; i += 256) cnt[i] = 0;
  if (tid < 64) dbase[tid] = 0;
  __syncthreads();
  int ecnt = bcur[t*NB + b]; if (ecnt > CAP) ecnt = CAP;
  const uchar_t* dp = sdst8 + (size_t)(t*NB + b)*CAP;
  for (int i = tid; i < ecnt; i += 256)
    atomicAdd(&cnt[dp[i]], 1);
  __syncthreads();
  int v = (tid < DPB) ? cnt[tid] : 0;
  int pc = (v + 7) & ~7;                      // padded count -> aligned chains
  int excl;
  {
    int lane = tid & 63, wid = tid >> 6;
    int x = pc;
    #pragma unroll
    for (int o = 1; o < 64; o <<= 1){
      int y = __shfl_up(x, o, 64);
      if (lane >= o) x += y;
    }
    if (lane == 63) wsum[wid] = x;
    __syncthreads();
    if (tid == 0){
      int s = 0;
      #pragma unroll
      for (int w = 0; w < 4; w++){ int tmp = wsum[w]; wsum[w] = s; s += tmp; }
    }
    __syncthreads();
    excl = x - pc + wsum[wid];
  }
  // descending-degree counting sort (class 0 = largest degree)
  int cls = 63 - ((v > 63) ? 63 : v);
  if (tid < DPB){
    sdinv[tid] = rsqrtf((float)(v + 1));      // +1 self loop
    atomicAdd(&dbase[cls], 1);
  }
  __syncthreads();
  if (tid == 0){
    int s = 0;
    for (int i = 0; i < 64; i++){ int c = dbase[i]; dbase[i] = s; s += c; }
  }
  __syncthreads();
  if (tid < DPB){
    int r = atomicAdd(&dbase[cls], 1);
    int cv = (v > 2047) ? 2047 : v;
    ordg[(size_t)(t*NB + b)*DPB + r] = (excl << 19) | (cv << 8) | tid;
  }
  // fused cvt+scale for this block's nodes (sdinv visible via barriers above)
  const float4* xt = x4 + (size_t)t*NN*8;
  ushort4*     xbt = xb4 + (size_t)t*NN*8;
  for (int i = tid; i < DPB*8; i += 256){
    int d = i >> 3, f = i & 7;
    int n = b*DPB + d;
    if (n < NN){
      float dn = sdinv[d];
      float4 vv = xt[(size_t)n*8 + f];
      ushort4 o;
      o.x = f2b(vv.x*dn); o.y = f2b(vv.y*dn); o.z = f2b(vv.z*dn); o.w = f2b(vv.w*dn);
      xbt[(size_t)n*8 + f] = o;
    }
  }
}

// ---------------- bucket gather v12 (R10 verbatim): XCD swizzle + LPT claiming -
__global__ __launch_bounds__(256) void gatherb_kernel(const ushort_t* __restrict__ xbs,
                                                      const ushort_t* __restrict__ ssrc16,
                                                      const uchar_t* __restrict__ sdst8,
                                                      const int* __restrict__ bcur,
                                                      const int* __restrict__ ordg,
                                                      ushort_t* __restrict__ aggb){
  int l = blockIdx.x;
  int wk = ((l & 7) * 192) + (l >> 3);   // XCD l%8 owns contiguous slabs
  int t = wk >> 8;
  int b = wk & 255;
  int tid = threadIdx.x;
  __shared__ __align__(16) ushort_t ssrc[SCAP];  // 9 KB dst-sorted srcs, chains 8-aligned
  __shared__ int sord[DPB];           // rank-indexed packed (off<<19)|(cnt<<8)|dst
  __shared__ int scnt[DPB];           // per-dst rank cursor
  __shared__ int dcur;                // dynamic rank claim cursor
  int ecnt = bcur[t*NB + b]; if (ecnt > CAP) ecnt = CAP;
  size_t slab = (size_t)(t*NB + b)*CAP;
  const ushort_t* sp = ssrc16 + slab;
  const uchar_t*  dp = sdst8 + slab;
  const int* og = ordg + (size_t)(t*NB + b)*DPB;
  if (tid < DPB){
    int e = og[tid];                  // rank tid entry
    sord[tid] = e;
    scnt[e & 255] = (unsigned)e >> 19;  // per-dst chain start
  }
  if (tid == 0) dcur = 0;
  __syncthreads();
  // rank & place (single pass over slab)
  for (int e = tid; e < ecnt; e += 256){
    int d = dp[e];
    int pos = atomicAdd(&scnt[d], 1);
    if (pos < SCAP) ssrc[pos] = sp[e];
  }
  __syncthreads();
  // reduce: 8-lane group claims ranks in LPT order
  int lane = tid & 63;
  int fp = lane & 7;
  const uint2* xb2 = (const uint2*)xbs + (size_t)t*NN*8;
  uint2* agg2 = (uint2*)aggb + (size_t)t*NN*8;
  while (true){
    int r = 0;
    if ((lane & 7) == 0) r = atomicAdd(&dcur, 1);
    r = __shfl(r, lane & 56, 64);
    if (r >= DPB) break;
    int pv = sord[r];
    int e0 = (unsigned)pv >> 19;
    int deg = (pv >> 8) & 2047;
    int ld = pv & 255;
    int e1 = e0 + deg;
    f32x2 a01 = {0.f, 0.f}, a23 = {0.f, 0.f};
    for (int i = e0; i < e1; i += 8){
      short8 sv = *(const short8*)&ssrc[i];   // one b128: 8 src ids (broadcast)
      uint2 rr[8];
      #pragma unroll
      for (int k = 0; k < 8; k++){
        int sidx = (int)(ushort_t)sv[k];
        rr[k] = xb2[(size_t)sidx*8 + fp];
      }
      int rem = e1 - i;
      #pragma unroll
      for (int k = 0; k < 8; k++){
        if (k >= rem){ rr[k].x = 0u; rr[k].y = 0u; }
        f32x2 v01 = {lo16f(rr[k].x), hi16f(rr[k].x)};
        f32x2 v23 = {lo16f(rr[k].y), hi16f(rr[k].y)};
        a01 += v01;
        a23 += v23;
      }
    }
    int n = b*DPB + ld;
    if (n < NN){
      float dn = rsqrtf((float)(deg + 1));      // local degree -> dinv
      uint2 sv = xb2[(size_t)n*8 + fp];         // self term (pre-scaled row)
      float o0 = dn*(a01[0] + lo16f(sv.x));
      float o1 = dn*(a01[1] + hi16f(sv.x));
      float o2 = dn*(a23[0] + lo16f(sv.y));
      float o3 = dn*(a23[1] + hi16f(sv.y));
      uint2 pk;
      pk.x = (unsigned)f2b(o0) | ((unsigned)f2b(o1) << 16);
      pk.y = (unsigned)f2b(o2) | ((unsigned)f2b(o3) << 16);
      agg2[(size_t)n*8 + fp] = pk;
    }
  }
}

// ---------------- ALL GRU steps v2: h in registers, rcp gates, direct A loads ---
__global__ __launch_bounds__(256) void gates_kernel(const ushort_t* __restrict__ aggb,
                                                    const float* __restrict__ wbias,
                                                    const short* __restrict__ wfrag,
                                                    float* __restrict__ out){
  __shared__ __align__(16) short Hsp[4096];   // 64 x 64  (8 KB) swizzled
  __shared__ __align__(16) short HRp[4096];   // 64 x 64  (8 KB) swizzled
  int tid = threadIdx.x;
  int nb = blockIdx.x*64;
  int wv = tid >> 6, lane = tid & 63;
  int q = lane >> 4, l15 = lane & 15;
  #pragma unroll
  for (int r = 0; r < 8; r++) ((int*)Hsp)[tid + 256*r] = 0;
  short8 wz[3], wr[3], wh[3];
  #pragma unroll
  for (int kc = 0; kc < 3; kc++){
    wz[kc] = ((const short8*)wfrag)[(wv*3 + kc)*64 + lane];
    wr[kc] = ((const short8*)wfrag)[((wv+4)*3 + kc)*64 + lane];
    wh[kc] = ((const short8*)wfrag)[(24 + wv*3 + kc)*64 + lane];
  }
  int jz = wv*16 + l15;
  float cz = wbias[jz], cr = wbias[64 + jz], ch = wbias[128 + jz];
  int c0 = jz >> 3, jl = jz & 7, x0 = c0 & 7;
  int sq0 = q & 7, sq1 = (4 + q) & 7;         // swizzle keys for chunk q / 4+q
  float hreg[4][4];
  #pragma unroll
  for (int mt = 0; mt < 4; mt++)
    #pragma unroll
    for (int e = 0; e < 4; e++) hreg[mt][e] = 0.f;
  f32x4 accZ[4], accH[4];
  const short8* agf = (const short8*)aggb;
  for (int t = 0; t < TT; t++){
    // direct global A-fragment loads (issued before barrier; tile is L1-hot)
    short8 fac[4];
    #pragma unroll
    for (int mt = 0; mt < 4; mt++){
      int gn = nb + mt*16 + l15;
      short8 v = {0,0,0,0,0,0,0,0};
      if (gn < NN) v = agf[((size_t)t*NN + gn)*4 + q];
      fac[mt] = v;
    }
    __syncthreads();   // prev-iter Hsp writes visible
    #pragma unroll
    for (int mt = 0; mt < 4; mt++){
      int n = mt*16 + l15;
      short8 fh0 = *(const short8*)&Hsp[((q)*64   + (n ^ sq0))*8];
      short8 fh1 = *(const short8*)&Hsp[((4+q)*64 + (n ^ sq1))*8];
      f32x4 az = {0.f,0.f,0.f,0.f}, ar = {0.f,0.f,0.f,0.f};
      az = __builtin_amdgcn_mfma_f32_16x16x32_bf16(fac[mt], wz[0], az, 0,0,0);
      az = __builtin_amdgcn_mfma_f32_16x16x32_bf16(fh0,     wz[1], az, 0,0,0);
      az = __builtin_amdgcn_mfma_f32_16x16x32_bf16(fh1,     wz[2], az, 0,0,0);
      ar = __builtin_amdgcn_mfma_f32_16x16x32_bf16(fac[mt], wr[0], ar, 0,0,0);
      ar = __builtin_amdgcn_mfma_f32_16x16x32_bf16(fh0,     wr[1], ar, 0,0,0);
      ar = __builtin_amdgcn_mfma_f32_16x16x32_bf16(fh1,     wr[2], ar, 0,0,0);
      accZ[mt] = az; accH[mt] = ar;
    }
    #pragma unroll
    for (int mt = 0; mt < 4; mt++){
      #pragma unroll
      for (int e = 0; e < 4; e++){
        int node = mt*16 + q*4 + e;
        float z = __builtin_amdgcn_rcpf(1.f + __expf(-(accZ[mt][e] + cz)));
        float r = __builtin_amdgcn_rcpf(1.f + __expf(-(accH[mt][e] + cr)));
        HRp[(c0*64 + (node ^ x0))*8 + jl] = (short)f2b(hreg[mt][e] * r);
        accZ[mt][e] = z;
      }
    }
    __syncthreads();   // HRp complete
    #pragma unroll
    for (int mt = 0; mt < 4; mt++){
      int n = mt*16 + l15;
      short8 fr0 = *(const short8*)&HRp[((q)*64   + (n ^ sq0))*8];
      short8 fr1 = *(const short8*)&HRp[((4+q)*64 + (n ^ sq1))*8];
      f32x4 ahh = {0.f,0.f,0.f,0.f};
      ahh = __builtin_amdgcn_mfma_f32_16x16x32_bf16(fac[mt], wh[0], ahh, 0,0,0);
      ahh = __builtin_amdgcn_mfma_f32_16x16x32_bf16(fr0,     wh[1], ahh, 0,0,0);
      ahh = __builtin_amdgcn_mfma_f32_16x16x32_bf16(fr1,     wh[2], ahh, 0,0,0);
      accH[mt] = ahh;
    }
    #pragma unroll
    for (int mt = 0; mt < 4; mt++){
      #pragma unroll
      for (int e = 0; e < 4; e++){
        int node = mt*16 + q*4 + e;
        float xv = accH[mt][e] + ch;
        float ex = __expf(-2.f*fabsf(xv));
        float th = (1.f - ex) * __builtin_amdgcn_rcpf(1.f + ex);
        th = (xv < 0.f) ? -th : th;
        float z = accZ[mt][e];
        float hv = z*hreg[mt][e] + (1.f - z)*th;
        hreg[mt][e] = hv;
        Hsp[(c0*64 + (node ^ x0))*8 + jl] = (short)f2b(hv);
      }
    }
  }
  __syncthreads();
  short8 wo0 = ((const short8*)wfrag)[36*64 + lane];
  short8 wo1 = ((const short8*)wfrag)[37*64 + lane];
  int no = wv*16 + l15;
  short8 f0 = *(const short8*)&Hsp[((q)*64   + (no ^ sq0))*8];
  short8 f1 = *(const short8*)&Hsp[((4+q)*64 + (no ^ sq1))*8];
  f32x4 ao = {0.f,0.f,0.f,0.f};
  ao = __builtin_amdgcn_mfma_f32_16x16x32_bf16(f0, wo0, ao, 0,0,0);
  ao = __builtin_amdgcn_mfma_f32_16x16x32_bf16(f1, wo1, ao, 0,0,0);
  float ob = wbias[192 + l15];
  #pragma unroll
  for (int e = 0; e < 4; e++){
    int gn = nb + wv*16 + q*4 + e;
    if (gn < NN) out[gn*OO + l15] = ao[e] + ob;
  }
}

extern "C" void kernel_launch(void* const* d_in, const int* in_sizes, int n_in,
                              void* d_out, int out_size, void* d_ws, size_t ws_size,
                              hipStream_t stream) {
  const float* xs = (const float*)d_in[0];
  const int*   ei = (const int*)d_in[1];
  float* out = (float*)d_out;
  char* ws = (char*)d_ws;
  // workspace layout (bytes); total 59,724,544 (same proven footprint)
  ushort_t*  aggb   = (ushort_t*)(ws + 0);           // 19,200,000
  ushort_t*  xbs    = (ushort_t*)(ws + 19200000);    // 19,200,000 (pre-scaled bf16)
  ushort_t*  ssrc16 = (ushort_t*)(ws + 38400000);    // 12,582,912
  uchar_t*   sdst8  = (uchar_t*) (ws + 50982912);    //  6,291,456
  // (old dinv slot ws+57274368, 1.2MB: unused)
  int*       bcur   = (int*)     (ws + 58474368);    //  6,144
  short*     wfrag  = (short*)   (ws + 58480512);    //  38,912
  float*     wbias  = (float*)   (ws + 58519424);    //  832
  int*       ordg   = (int*)     (ws + 58520320);    //  1,204,224 -> end 59,724,544

  prepall_kernel<<<77, 256, 0, stream>>>(
      (const float*)d_in[2],(const float*)d_in[3],(const float*)d_in[4],(const float*)d_in[5],
      (const float*)d_in[6],(const float*)d_in[7],(const float*)d_in[8],(const float*)d_in[9],
      (const float*)d_in[10],(const float*)d_in[11],(const float*)d_in[12],(const float*)d_in[13],
      (const float*)d_in[14],(const float*)d_in[15], wfrag, wbias, bcur);
  scatter_kernel<<<dim3((EE + CHUNK-1)/CHUNK, TT), 256, 0, stream>>>(ei, bcur, ssrc16, sdst8);
  degcvt_kernel<<<dim3(NB, TT), 256, 0, stream>>>(sdst8, bcur, (const float4*)xs, (ushort4*)xbs, ordg);
  gatherb_kernel<<<NB*TT, 256, 0, stream>>>(xbs, ssrc16, sdst8, bcur, ordg, aggb);
  gates_kernel<<<(NN + 63)/64, 256, 0, stream>>>(aggb, wbias, wfrag, out);
}

// Round 14
// 230.602 us; speedup vs baseline: 1.7625x; 1.0349x over previous
//
#include <hip/hip_runtime.h>
#include <hip/hip_bf16.h>

#define TT 6
#define NN 50000
#define EE 800000
#define FF 32
#define HH 64
#define OO 16

#define NB 256        // dst buckets
#define DPB 196       // dsts per bucket (256*196 = 50176 >= 50000)
#define CHUNK 4096    // edges per block in scatter
#define CAP 4096      // slab capacity per (t,bucket): mean 3125, sd 56 -> 17 sigma
#define SCAP 4608     // 8-aligned-chain LDS capacity: mean 3811, sd ~32 -> 12 sigma

#define WFRAG_N 19456  // 38 slots * 512 bf16 fragment-packed weights
// wbias layout: [0..63] cz, [64..127] cr, [128..191] ch, [192..207] out_b

typedef unsigned short ushort_t;
typedef unsigned char uchar_t;
typedef short short8 __attribute__((ext_vector_type(8)));   // 8 bf16 (4 VGPRs)
typedef float f32x4 __attribute__((ext_vector_type(4)));
typedef float f32x2 __attribute__((ext_vector_type(2)));

__device__ __forceinline__ float ubf(ushort_t v){ return __uint_as_float(((unsigned)v) << 16); }
__device__ __forceinline__ ushort_t f2b(float f){
  unsigned u = __float_as_uint(f);
  return (ushort_t)((u + 0x7FFFu + ((u >> 16) & 1u)) >> 16);
}
__device__ __forceinline__ float lo16f(unsigned u){ return __uint_as_float(u << 16); }
__device__ __forceinline__ float hi16f(unsigned u){ return __uint_as_float(u & 0xFFFF0000u); }

// LESSON (v7/v8): LDS *float* atomics on gfx950 are lane-serialized (~820us for
// 153M) -- never bulk f32 LDS atomics. Int LDS atomics are fine.
// LESSON (v11/R9): blocks dispatch round-robin to XCDs (l%8), whole grid
// co-resident; identity (t,b) mapping -> 19.2MB/XCD L2 working set -> thrash
// (FETCH 243MB, 80us). Contiguous-range swizzle wk=(l&7)*192+(l>>3) is right.
// LESSON (v13/R11): bulk random-address GLOBAL atomics are ~40ns each on gfx950
// (4.8M made scatter 200us, VALUBusy 2.6%, L2 dirty-line thrash). Histogram in
// LDS (int atomics) per block instead.
// NOTE (R12/R13): "container failed twice" on a clean-audited kernel was infra
// flake -- identical source passed next round. Resubmit once before reverting.

// ---------------- fused prep: wfrag (direct from raw weights) + biases + bcur zero
__global__ void prepall_kernel(const float* __restrict__ Wz,const float* __restrict__ bz,
                               const float* __restrict__ Wr,const float* __restrict__ br,
                               const float* __restrict__ Wh,const float* __restrict__ bh,
                               const float* __restrict__ Lz,const float* __restrict__ Lzb,
                               const float* __restrict__ Lr,const float* __restrict__ Lrb,
                               const float* __restrict__ Lh,const float* __restrict__ Lhb,
                               const float* __restrict__ oW,const float* __restrict__ ob,
                               short* __restrict__ wfrag, float* __restrict__ wbias,
                               int* __restrict__ bcur){
  int bid = blockIdx.x, tid = threadIdx.x;
  if (bid < 76){
    int idx = bid*256 + tid;   // 0..19455
    int slot = idx >> 9, lane = (idx >> 3) & 63, j = idx & 7;
    int q = lane >> 4, l15 = lane & 15;
    float val;
    if (slot < 36){
      int g, kc, ncol;
      if (slot < 24){ int nt = slot/3; kc = slot - nt*3; ncol = nt*16 + l15;
                      g = (ncol < 64) ? 0 : 1; ncol &= 63; }
      else          { int s2 = slot-24; int nt = s2/3; kc = s2 - nt*3;
                      ncol = nt*16 + l15; g = 2; }
      const float* W = (g==0)?Wz:((g==1)?Wr:Wh);     // [32][64]
      const float* L = (g==0)?Lz:((g==1)?Lr:Lh);     // [128][64]
      int k = kc*32 + q*8 + j;                        // 0..95
      if (k < 32){                                    // fused W@L[:64]
        float s = 0.f;
        for (int m = 0; m < 64; m++) s += W[k*64+m] * L[m*64+ncol];
        val = s;
      } else val = L[(32+k)*64 + ncol];               // L rows 64..127
    } else {
      int kc = slot - 36;
      int k = kc*32 + q*8 + j;                        // 0..63
      val = oW[k*16 + l15];
    }
    wfrag[idx] = (short)f2b(val);
  } else {
    if (tid < 192){
      int g = tid >> 6, j = tid & 63;
      const float* L  = (g==0)?Lz:((g==1)?Lr:Lh);
      const float* bb = (g==0)?bz:((g==1)?br:bh);
      const float* Lb = (g==0)?Lzb:((g==1)?Lrb:Lhb);
      float s = Lb[j];
      for (int m = 0; m < 64; m++) s += bb[m] * L[m*64+j];
      wbias[tid] = s;
    } else if (tid < 208){
      wbias[tid] = ob[tid-192];
    }
    for (int i = tid; i < 1536; i += 256) bcur[i] = 0;
  }
}

// ---------------- scatter: LDS counting-sort by bucket -> coalesced slab writes --
__global__ __launch_bounds__(256) void scatter_kernel(const int* __restrict__ ei,
                                                      int* __restrict__ bcur,
                                                      ushort_t* __restrict__ ssrc16,
                                                      uchar_t* __restrict__ sdst8){
  int t = blockIdx.y;
  __shared__ int cnt[NB];
  __shared__ int lstart[NB];
  __shared__ int gbase[NB];
  __shared__ int wsum[4];
  __shared__ ushort_t spay[CHUNK];
  __shared__ uchar_t  sdlo[CHUNK];
  __shared__ uchar_t  sbk[CHUNK];
  int tid = threadIdx.x;
  cnt[tid] = 0;
  __syncthreads();
  int e0 = blockIdx.x*CHUNK;
  const int* srcs = ei + t*2*EE;
  const int* dsts = ei + t*2*EE + EE;
  int pk[CHUNK/256];
  int ps[CHUNK/256];
  int pd[CHUNK/256];
  #pragma unroll
  for (int i = 0; i < CHUNK/256; i++){
    int e = e0 + i*256 + tid;
    if (e < EE){
      int s = srcs[e], d = dsts[e];
      int b = d / DPB;
      int lr = atomicAdd(&cnt[b], 1);
      pk[i] = (b << 12) | lr;
      ps[i] = s;
      pd[i] = d - b*DPB;
    } else pk[i] = -1;
  }
  __syncthreads();
  {
    int v = cnt[tid];
    int lane = tid & 63, wid = tid >> 6;
    int x = v;
    #pragma unroll
    for (int o = 1; o < 64; o <<= 1){
      int y = __shfl_up(x, o, 64);
      if (lane >= o) x += y;
    }
    if (lane == 63) wsum[wid] = x;
    __syncthreads();
    if (tid == 0){
      int s = 0;
      #pragma unroll
      for (int w = 0; w < 4; w++){ int tmp = wsum[w]; wsum[w] = s; s += tmp; }
    }
    __syncthreads();
    lstart[tid] = x - v + wsum[wid];
    gbase[tid] = (v > 0) ? atomicAdd(&bcur[t*NB + tid], v) : 0;
  }
  __syncthreads();
  #pragma unroll
  for (int i = 0; i < CHUNK/256; i++){
    if (pk[i] >= 0){
      int b = pk[i] >> 12, lr = pk[i] & 4095;
      int pos = lstart[b] + lr;
      spay[pos] = (ushort_t)ps[i];
      sdlo[pos] = (uchar_t)pd[i];
      sbk[pos]  = (uchar_t)b;
    }
  }
  __syncthreads();
  int nE = EE - e0; if (nE > CHUNK) nE = CHUNK;
  for (int i = tid; i < nE; i += 256){
    int b = sbk[i];
    int gpos = gbase[b] + (i - lstart[b]);
    if (gpos < CAP){
      size_t sb = (size_t)(t*NB + b)*CAP + gpos;
      ssrc16[sb] = spay[i];
      sdst8[sb]  = sdlo[i];
    }
  }
}

// ---------------- degree + LPT order + fused convert/pre-scale -----------------
__global__ __launch_bounds__(256) void degcvt_kernel(const uchar_t* __restrict__ sdst8,
                                                     const int* __restrict__ bcur,
                                                     const float4* __restrict__ x4,
                                                     ushort4* __restrict__ xb4,
                                                     int* __restrict__ ordg){
  int b = blockIdx.x, t = blockIdx.y, tid = threadIdx.x;
  __shared__ int cnt[DPB];
  __shared__ int wsum[4];
  __shared__ int dbase[64];
  __shared__ float sdinv[DPB];
  for (int i = tid; i < DPB; i += 256) cnt[i] = 0;
  if (tid < 64) dbase[tid] = 0;
  __syncthreads();
  int ecnt = bcur[t*NB + b]; if (ecnt > CAP) ecnt = CAP;
  const uchar_t* dp = sdst8 + (size_t)(t*NB + b)*CAP;
  for (int i = tid; i < ecnt; i += 256)
    atomicAdd(&cnt[dp[i]], 1);
  __syncthreads();
  int v = (tid < DPB) ? cnt[tid] : 0;
  int pc = (v + 7) & ~7;                      // padded count -> aligned chains
  int excl;
  {
    int lane = tid & 63, wid = tid >> 6;
    int x = pc;
    #pragma unroll
    for (int o = 1; o < 64; o <<= 1){
      int y = __shfl_up(x, o, 64);
      if (lane >= o) x += y;
    }
    if (lane == 63) wsum[wid] = x;
    __syncthreads();
    if (tid == 0){
      int s = 0;
      #pragma unroll
      for (int w = 0; w < 4; w++){ int tmp = wsum[w]; wsum[w] = s; s += tmp; }
    }
    __syncthreads();
    excl = x - pc + wsum[wid];
  }
  // descending-degree counting sort (class 0 = largest degree)
  int cls = 63 - ((v > 63) ? 63 : v);
  if (tid < DPB){
    sdinv[tid] = rsqrtf((float)(v + 1));      // +1 self loop
    atomicAdd(&dbase[cls], 1);
  }
  __syncthreads();
  if (tid == 0){
    int s = 0;
    for (int i = 0; i < 64; i++){ int c = dbase[i]; dbase[i] = s; s += c; }
  }
  __syncthreads();
  if (tid < DPB){
    int r = atomicAdd(&dbase[cls], 1);
    int cv = (v > 2047) ? 2047 : v;
    ordg[(size_t)(t*NB + b)*DPB + r] = (excl << 19) | (cv << 8) | tid;
  }
  // fused cvt+scale for this block's nodes (sdinv visible via barriers above)
  const float4* xt = x4 + (size_t)t*NN*8;
  ushort4*     xbt = xb4 + (size_t)t*NN*8;
  for (int i = tid; i < DPB*8; i += 256){
    int d = i >> 3, f = i & 7;
    int n = b*DPB + d;
    if (n < NN){
      float dn = sdinv[d];
      float4 vv = xt[(size_t)n*8 + f];
      ushort4 o;
      o.x = f2b(vv.x*dn); o.y = f2b(vv.y*dn); o.z = f2b(vv.z*dn); o.w = f2b(vv.w*dn);
      xbt[(size_t)n*8 + f] = o;
    }
  }
}

// ---------------- bucket gather v14: wide place pass + 4-lane dst groups -------
// vs v13 (47.5us, VGPR 20, VALUBusy 36%): (a) place pass handles 4 consecutive
// edges/thread via one uchar4 + one ushort4 load (4x MLP, 4x fewer load insts);
// (b) reduce uses 4-lane groups x uint4 rows (same 64B/row) -> 16 concurrent
// dsts/wave (2x) and 8 dwordx4 loads in flight per lane (~60 VGPR, breaking the
// 20-VGPR latency-serialized schedule). Claim/LPT/epilogue logic unchanged.
__global__ __launch_bounds__(256) void gatherb_kernel(const ushort_t* __restrict__ xbs,
                                                      const ushort_t* __restrict__ ssrc16,
                                                      const uchar_t* __restrict__ sdst8,
                                                      const int* __restrict__ bcur,
                                                      const int* __restrict__ ordg,
                                                      ushort_t* __restrict__ aggb){
  int l = blockIdx.x;
  int wk = ((l & 7) * 192) + (l >> 3);   // XCD l%8 owns contiguous slabs
  int t = wk >> 8;
  int b = wk & 255;
  int tid = threadIdx.x;
  __shared__ __align__(16) ushort_t ssrc[SCAP];  // 9 KB dst-sorted srcs, chains 8-aligned
  __shared__ int sord[DPB];           // rank-indexed packed (off<<19)|(cnt<<8)|dst
  __shared__ int scnt[DPB];           // per-dst place cursor
  __shared__ int dcur;                // dynamic rank claim cursor
  int ecnt = bcur[t*NB + b]; if (ecnt > CAP) ecnt = CAP;
  size_t slab = (size_t)(t*NB + b)*CAP;
  const ushort_t* sp = ssrc16 + slab;
  const uchar_t*  dp = sdst8 + slab;
  const int* og = ordg + (size_t)(t*NB + b)*DPB;
  if (tid < DPB){
    int e = og[tid];                  // rank tid entry
    sord[tid] = e;
    scnt[e & 255] = (unsigned)e >> 19;  // per-dst chain start
  }
  if (tid == 0) dcur = 0;
  __syncthreads();
  // place: 4 consecutive edges per thread-iter (uchar4 + ushort4 loads)
  for (int e4 = tid*4; e4 < ecnt; e4 += 1024){
    uchar4  d4 = *(const uchar4*)&dp[e4];   // within CAP slab, safe past ecnt
    ushort4 s4 = *(const ushort4*)&sp[e4];
    int rem = ecnt - e4;
    {          int pos = atomicAdd(&scnt[d4.x], 1); if (pos < SCAP) ssrc[pos] = s4.x; }
    if (rem > 1){ int pos = atomicAdd(&scnt[d4.y], 1); if (pos < SCAP) ssrc[pos] = s4.y; }
    if (rem > 2){ int pos = atomicAdd(&scnt[d4.z], 1); if (pos < SCAP) ssrc[pos] = s4.z; }
    if (rem > 3){ int pos = atomicAdd(&scnt[d4.w], 1); if (pos < SCAP) ssrc[pos] = s4.w; }
  }
  __syncthreads();
  // reduce: 4-lane group = 1 dst (16 groups/wave); uint4 row slices
  int lane = tid & 63;
  int fp = lane & 3;
  const uint4* xb4v = (const uint4*)xbs + (size_t)t*NN*4;
  uint4* agg4 = (uint4*)aggb + (size_t)t*NN*4;
  while (true){
    int r = 0;
    if ((lane & 3) == 0) r = atomicAdd(&dcur, 1);
    r = __shfl(r, lane & 60, 64);
    if (r >= DPB) break;
    int pv = sord[r];
    int e0 = (unsigned)pv >> 19;
    int deg = (pv >> 8) & 2047;
    int ld = pv & 255;
    int e1 = e0 + deg;
    f32x2 a01 = {0.f,0.f}, a23 = {0.f,0.f}, a45 = {0.f,0.f}, a67 = {0.f,0.f};
    for (int i = e0; i < e1; i += 8){
      short8 sv = *(const short8*)&ssrc[i];   // one b128: 8 src ids (broadcast)
      uint4 rr[8];
      #pragma unroll
      for (int k = 0; k < 8; k++){
        int sidx = (int)(ushort_t)sv[k];
        rr[k] = xb4v[(size_t)sidx*4 + fp];
      }
      int rem = e1 - i;
      #pragma unroll
      for (int k = 0; k < 8; k++){
        if (k >= rem){ rr[k].x = 0u; rr[k].y = 0u; rr[k].z = 0u; rr[k].w = 0u; }
        f32x2 v01 = {lo16f(rr[k].x), hi16f(rr[k].x)};
        f32x2 v23 = {lo16f(rr[k].y), hi16f(rr[k].y)};
        f32x2 v45 = {lo16f(rr[k].z), hi16f(rr[k].z)};
        f32x2 v67 = {lo16f(rr[k].w), hi16f(rr[k].w)};
        a01 += v01; a23 += v23; a45 += v45; a67 += v67;
      }
    }
    int n = b*DPB + ld;
    if (n < NN){
      float dn = rsqrtf((float)(deg + 1));      // local degree -> dinv
      uint4 sv2 = xb4v[(size_t)n*4 + fp];       // self term (pre-scaled row)
      float o0 = dn*(a01[0] + lo16f(sv2.x));
      float o1 = dn*(a01[1] + hi16f(sv2.x));
      float o2 = dn*(a23[0] + lo16f(sv2.y));
      float o3 = dn*(a23[1] + hi16f(sv2.y));
      float o4 = dn*(a45[0] + lo16f(sv2.z));
      float o5 = dn*(a45[1] + hi16f(sv2.z));
      float o6 = dn*(a67[0] + lo16f(sv2.w));
      float o7 = dn*(a67[1] + hi16f(sv2.w));
      uint4 pk;
      pk.x = (unsigned)f2b(o0) | ((unsigned)f2b(o1) << 16);
      pk.y = (unsigned)f2b(o2) | ((unsigned)f2b(o3) << 16);
      pk.z = (unsigned)f2b(o4) | ((unsigned)f2b(o5) << 16);
      pk.w = (unsigned)f2b(o6) | ((unsigned)f2b(o7) << 16);
      agg4[(size_t)n*4 + fp] = pk;
    }
  }
}

// ---------------- ALL GRU steps v2: h in registers, rcp gates, direct A loads ---
__global__ __launch_bounds__(256) void gates_kernel(const ushort_t* __restrict__ aggb,
                                                    const float* __restrict__ wbias,
                                                    const short* __restrict__ wfrag,
                                                    float* __restrict__ out){
  __shared__ __align__(16) short Hsp[4096];   // 64 x 64  (8 KB) swizzled
  __shared__ __align__(16) short HRp[4096];   // 64 x 64  (8 KB) swizzled
  int tid = threadIdx.x;
  int nb = blockIdx.x*64;
  int wv = tid >> 6, lane = tid & 63;
  int q = lane >> 4, l15 = lane & 15;
  #pragma unroll
  for (int r = 0; r < 8; r++) ((int*)Hsp)[tid + 256*r] = 0;
  short8 wz[3], wr[3], wh[3];
  #pragma unroll
  for (int kc = 0; kc < 3; kc++){
    wz[kc] = ((const short8*)wfrag)[(wv*3 + kc)*64 + lane];
    wr[kc] = ((const short8*)wfrag)[((wv+4)*3 + kc)*64 + lane];
    wh[kc] = ((const short8*)wfrag)[(24 + wv*3 + kc)*64 + lane];
  }
  int jz = wv*16 + l15;
  float cz = wbias[jz], cr = wbias[64 + jz], ch = wbias[128 + jz];
  int c0 = jz >> 3, jl = jz & 7, x0 = c0 & 7;
  int sq0 = q & 7, sq1 = (4 + q) & 7;         // swizzle keys for chunk q / 4+q
  float hreg[4][4];
  #pragma unroll
  for (int mt = 0; mt < 4; mt++)
    #pragma unroll
    for (int e = 0; e < 4; e++) hreg[mt][e] = 0.f;
  f32x4 accZ[4], accH[4];
  const short8* agf = (const short8*)aggb;
  for (int t = 0; t < TT; t++){
    // direct global A-fragment loads (issued before barrier; tile is L1-hot)
    short8 fac[4];
    #pragma unroll
    for (int mt = 0; mt < 4; mt++){
      int gn = nb + mt*16 + l15;
      short8 v = {0,0,0,0,0,0,0,0};
      if (gn < NN) v = agf[((size_t)t*NN + gn)*4 + q];
      fac[mt] = v;
    }
    __syncthreads();   // prev-iter Hsp writes visible
    #pragma unroll
    for (int mt = 0; mt < 4; mt++){
      int n = mt*16 + l15;
      short8 fh0 = *(const short8*)&Hsp[((q)*64   + (n ^ sq0))*8];
      short8 fh1 = *(const short8*)&Hsp[((4+q)*64 + (n ^ sq1))*8];
      f32x4 az = {0.f,0.f,0.f,0.f}, ar = {0.f,0.f,0.f,0.f};
      az = __builtin_amdgcn_mfma_f32_16x16x32_bf16(fac[mt], wz[0], az, 0,0,0);
      az = __builtin_amdgcn_mfma_f32_16x16x32_bf16(fh0,     wz[1], az, 0,0,0);
      az = __builtin_amdgcn_mfma_f32_16x16x32_bf16(fh1,     wz[2], az, 0,0,0);
      ar = __builtin_amdgcn_mfma_f32_16x16x32_bf16(fac[mt], wr[0], ar, 0,0,0);
      ar = __builtin_amdgcn_mfma_f32_16x16x32_bf16(fh0,     wr[1], ar, 0,0,0);
      ar = __builtin_amdgcn_mfma_f32_16x16x32_bf16(fh1,     wr[2], ar, 0,0,0);
      accZ[mt] = az; accH[mt] = ar;
    }
    #pragma unroll
    for (int mt = 0; mt < 4; mt++){
      #pragma unroll
      for (int e = 0; e < 4; e++){
        int node = mt*16 + q*4 + e;
        float z = __builtin_amdgcn_rcpf(1.f + __expf(-(accZ[mt][e] + cz)));
        float r = __builtin_amdgcn_rcpf(1.f + __expf(-(accH[mt][e] + cr)));
        HRp[(c0*64 + (node ^ x0))*8 + jl] = (short)f2b(hreg[mt][e] * r);
        accZ[mt][e] = z;
      }
    }
    __syncthreads();   // HRp complete
    #pragma unroll
    for (int mt = 0; mt < 4; mt++){
      int n = mt*16 + l15;
      short8 fr0 = *(const short8*)&HRp[((q)*64   + (n ^ sq0))*8];
      short8 fr1 = *(const short8*)&HRp[((4+q)*64 + (n ^ sq1))*8];
      f32x4 ahh = {0.f,0.f,0.f,0.f};
      ahh = __builtin_amdgcn_mfma_f32_16x16x32_bf16(fac[mt], wh[0], ahh, 0,0,0);
      ahh = __builtin_amdgcn_mfma_f32_16x16x32_bf16(fr0,     wh[1], ahh, 0,0,0);
      ahh = __builtin_amdgcn_mfma_f32_16x16x32_bf16(fr1,     wh[2], ahh, 0,0,0);
      accH[mt] = ahh;
    }
    #pragma unroll
    for (int mt = 0; mt < 4; mt++){
      #pragma unroll
      for (int e = 0; e < 4; e++){
        int node = mt*16 + q*4 + e;
        float xv = accH[mt][e] + ch;
        float ex = __expf(-2.f*fabsf(xv));
        float th = (1.f - ex) * __builtin_amdgcn_rcpf(1.f + ex);
        th = (xv < 0.f) ? -th : th;
        float z = accZ[mt][e];
        float hv = z*hreg[mt][e] + (1.f - z)*th;
        hreg[mt][e] = hv;
        Hsp[(c0*64 + (node ^ x0))*8 + jl] = (short)f2b(hv);
      }
    }
  }
  __syncthreads();
  short8 wo0 = ((const short8*)wfrag)[36*64 + lane];
  short8 wo1 = ((const short8*)wfrag)[37*64 + lane];
  int no = wv*16 + l15;
  short8 f0 = *(const short8*)&Hsp[((q)*64   + (no ^ sq0))*8];
  short8 f1 = *(const short8*)&Hsp[((4+q)*64 + (no ^ sq1))*8];
  f32x4 ao = {0.f,0.f,0.f,0.f};
  ao = __builtin_amdgcn_mfma_f32_16x16x32_bf16(f0, wo0, ao, 0,0,0);
  ao = __builtin_amdgcn_mfma_f32_16x16x32_bf16(f1, wo1, ao, 0,0,0);
  float ob = wbias[192 + l15];
  #pragma unroll
  for (int e = 0; e < 4; e++){
    int gn = nb + wv*16 + q*4 + e;
    if (gn < NN) out[gn*OO + l15] = ao[e] + ob;
  }
}

extern "C" void kernel_launch(void* const* d_in, const int* in_sizes, int n_in,
                              void* d_out, int out_size, void* d_ws, size_t ws_size,
                              hipStream_t stream) {
  const float* xs = (const float*)d_in[0];
  const int*   ei = (const int*)d_in[1];
  float* out = (float*)d_out;
  char* ws = (char*)d_ws;
  // workspace layout (bytes); total 59,724,544 (same proven footprint)
  ushort_t*  aggb   = (ushort_t*)(ws + 0);           // 19,200,000
  ushort_t*  xbs    = (ushort_t*)(ws + 19200000);    // 19,200,000 (pre-scaled bf16)
  ushort_t*  ssrc16 = (ushort_t*)(ws + 38400000);    // 12,582,912
  uchar_t*   sdst8  = (uchar_t*) (ws + 50982912);    //  6,291,456
  // (old dinv slot ws+57274368, 1.2MB: unused)
  int*       bcur   = (int*)     (ws + 58474368);    //  6,144
  short*     wfrag  = (short*)   (ws + 58480512);    //  38,912
  float*     wbias  = (float*)   (ws + 58519424);    //  832
  int*       ordg   = (int*)     (ws + 58520320);    //  1,204,224 -> end 59,724,544

  prepall_kernel<<<77, 256, 0, stream>>>(
      (const float*)d_in[2],(const float*)d_in[3],(const float*)d_in[4],(const float*)d_in[5],
      (const float*)d_in[6],(const float*)d_in[7],(const float*)d_in[8],(const float*)d_in[9],
      (const float*)d_in[10],(const float*)d_in[11],(const float*)d_in[12],(const float*)d_in[13],
      (const float*)d_in[14],(const float*)d_in[15], wfrag, wbias, bcur);
  scatter_kernel<<<dim3((EE + CHUNK-1)/CHUNK, TT), 256, 0, stream>>>(ei, bcur, ssrc16, sdst8);
  degcvt_kernel<<<dim3(NB, TT), 256, 0, stream>>>(sdst8, bcur, (const float4*)xs, (ushort4*)xbs, ordg);
  gatherb_kernel<<<NB*TT, 256, 0, stream>>>(xbs, ssrc16, sdst8, bcur, ordg, aggb);
  gates_kernel<<<(NN + 63)/64, 256, 0, stream>>>(aggb, wbias, wfrag, out);
}